// Round 8
// baseline (154.544 us; speedup 1.0000x reference)
//
#include <hip/hip_runtime.h>
#include <math.h>

#define T_STEPS 730
#define NB      1000
#define LENF    15
#define NEARZ   1e-5f

// ---------------------------------------------------------------------------
// DPP butterfly sum over each aligned group of 8 lanes, pure VALU:
// quad_perm xor1 (0xB1), quad_perm xor2 (0x4E), row_half_mirror (0x141).
// ---------------------------------------------------------------------------
template <int CTRL>
__device__ __forceinline__ float dpp_mov(float x) {
    int xi = __builtin_bit_cast(int, x);
    int r  = __builtin_amdgcn_update_dpp(0, xi, CTRL, 0xF, 0xF, true);
    return __builtin_bit_cast(float, r);
}
__device__ __forceinline__ float sum8(float v) {
    v += dpp_mov<0xB1>(v);
    v += dpp_mov<0x4E>(v);
    v += dpp_mov<0x141>(v);
    return v;   // all 8 lanes of the group hold the group sum
}

// One physics + reduce + FIR + store step. P folds to a constant after
// unrolling so hist[] stays register-resident.
#define STEP(CURV, P)                                                          \
  {                                                                            \
    float pcp = (CURV).x, pet = (CURV).y;                                      \
    float W     = pcp + S;                                                     \
    float term  = fmaf(W, inv2a, pb2a);                                        \
    float disc  = fmaf(term, term, -W * boa);                                  \
    float r     = __builtin_amdgcn_sqrtf(fmaxf(disc, NEARZ));                  \
    float Y     = term - r;                                                    \
    float e     = __builtin_amdgcn_exp2f(pet * ninvbl2);                       \
    float Sn    = Y * e;                                                       \
    float AET   = Y - Sn;                                                      \
    float avail = W - Y;                                                       \
    float Qs    = omc * avail;                                                 \
    float Gn    = fmaf(pc, avail, G) * inv1pd;                                 \
    float Qg    = pd * Gn;                                                     \
    S = Sn; G = Gn;                                                            \
    float qs_s = sum8(Qs);                                                     \
    float qg_s = sum8(Qg);                                                     \
    float ae_s = sum8(AET);                                                    \
    float s_s  = sum8(Sn);                                                     \
    float g_s  = sum8(Gn);                                                     \
    float v = qs_s + qg_s;                                                     \
    v = (m == 1) ? qs_s : v;                                                   \
    v = (m == 2) ? qg_s : v;                                                   \
    v = (m == 3) ? ae_s : v;                                                   \
    v = (m == 4) ? s_s  : v;                                                   \
    v = (m == 5) ? g_s  : v;                                                   \
    hist[(P)] = v;                                                             \
    float y0 = 0.0f, y1 = 0.0f, y2 = 0.0f;                                     \
    _Pragma("unroll")                                                          \
    for (int k = 0; k < LENF; k += 3)                                          \
        y0 = fmaf(wl[k], hist[((P) - k + 30) % LENF], y0);                     \
    _Pragma("unroll")                                                          \
    for (int k = 1; k < LENF; k += 3)                                          \
        y1 = fmaf(wl[k], hist[((P) - k + 30) % LENF], y1);                     \
    _Pragma("unroll")                                                          \
    for (int k = 2; k < LENF; k += 3)                                          \
        y2 = fmaf(wl[k], hist[((P) - k + 30) % LENF], y2);                     \
    *optr = (y0 + y1) + y2;                                                    \
    optr += incr;                                                              \
  }

// ---------------------------------------------------------------------------
// Fused scan + streaming FIR. Block = 64 = 1 wave = 8 basins x 8 members;
// grid = 125. ALL of x for the block's 8 basins is staged into LDS up-front
// (46.7 KB, coalesced float4 + ds_write_b128, ~1 us) -> the serial loop has
// ZERO vmem loads: no vmcnt drains, no exposed HBM latency (R6 post-mortem:
// chunk-boundary vmcnt drain cost ~90 cyc/step). Loop reads ds_read_b64 with
// wave-broadcast addresses and compile-time DS offsets; only vmem op left is
// the (never-waited-on) store. Single wave -> no s_barrier, just lgkmcnt.
// ---------------------------------------------------------------------------
__global__ __launch_bounds__(64, 1) void abcd_fused(const float* __restrict__ x,
                                                    const float* __restrict__ raw,
                                                    float* __restrict__ out,
                                                    float* __restrict__ dummy) {
    __shared__ float2 xs[T_STEPS * 8];     // [t*8 + lb], 46720 B

    const int L  = threadIdx.x;
    const int lb = L >> 3;                 // local basin 0..7
    const int m  = L & 7;                  // member / output-channel role
    const int b0 = blockIdx.x * 8;
    const int b  = b0 + lb;                // global basin

    // ---- bulk fill: 16 t-rows per float4 instruction, 46 iterations -------
    {
        const int tr = L >> 2;             // 0..15: t-row within iteration
        const int d4 = L & 3;              // 0..3: float4 within the row
        for (int i = 0; i < 46; ++i) {
            int t = i * 16 + tr;
            if (t < T_STEPS) {
                float4 v = *(const float4*)(x + (size_t)t * 2 * NB + b0 * 2 + d4 * 4);
                *(float4*)((float*)xs + t * 16 + d4 * 4) = v;
            }
        }
    }
    // single wave: ds_write->ds_read ordering handled by lgkmcnt, no barrier

    // raw layout (B,34) = [a(8), b(8), c(8), d(8), ra, rb]
    const float* rp = raw + b * 34;
    float pa = rp[0 * 8 + m] * 0.9f + 0.1f;
    float pb = rp[1 * 8 + m] * 450.0f + 50.0f;
    float pc = rp[2 * 8 + m];
    float pd = rp[3 * 8 + m] * 0.89f + 0.01f;

    float inv2a   = 1.0f / (2.0f * pa);
    float pb2a    = pb * inv2a;
    float boa     = pb / pa;
    float ninvbl2 = -1.4426950408889634f / pb;   // exp(-pet/b)=exp2(pet*this)
    float omc     = 1.0f - pc;
    float inv1pd  = 1.0f / (1.0f + pd);

    // gamma-UH weights (gammaln cancels under normalization); fold the /8
    // ensemble mean and the per-lane channel role into wl[].
    float ra_ = rp[32] * 2.9f;
    float rb_ = rp[33] * 6.5f;
    float aa  = fmaxf(ra_, 0.0f) + 0.1f;
    float th  = fmaxf(rb_, 0.0f) + 0.5f;
    float inv_th = 1.0f / th;
    float am1 = aa - 1.0f;
    float w[LENF];
    float sw = 0.0f;
#pragma unroll
    for (int k = 0; k < LENF; ++k) {
        float tt = (float)k + 0.5f;
        w[k] = __expf(am1 * __logf(tt) - tt * inv_th);
        sw += w[k];
    }
    float invs = 0.125f / sw;   // UH normalization x ensemble mean
    float wl[LENF];
#pragma unroll
    for (int k = 0; k < LENF; ++k) {
        float conv_w = w[k] * invs;                    // lanes 0..2: routed
        float pass_w = (k == 0) ? 0.125f : 0.0f;       // lanes 3..5: mean only
        float v2 = (m >= 3) ? pass_w : conv_w;
        wl[k] = (m >= 6) ? 0.0f : v2;                  // lanes 6,7: inert
    }

    // per-lane output pointer: lane m<6 -> channel m of basin b; else dummy.
    float* optr;
    long long incr;
    if (m < 6) { optr = out + (long long)b * 6 + m; incr = (long long)NB * 6; }
    else       { optr = dummy + (blockIdx.x * 64 + L); incr = 0; }

    float S = 50.0f, G = 10.0f;
    float hist[LENF];
#pragma unroll
    for (int k = 0; k < LENF; ++k) hist[k] = 0.0f;     // causal zero-history

    // loop-invariant LDS base; per-step offsets are compile-time immediates
    const float2* __restrict__ xp = xs + lb;

    // 48 x 15 steps + 10-step tail (720 % 15 == 0 keeps hist phase aligned)
    for (int i = 0; i < 48; ++i) {
        const int tb = i * 15;
#pragma unroll
        for (int j = 0; j < 15; ++j) {
            float2 cur = xp[(tb + j) * 8];
            STEP(cur, j);
        }
    }
#pragma unroll
    for (int j = 0; j < 10; ++j) {
        float2 cur = xp[(720 + j) * 8];
        STEP(cur, j);
    }
}

// ---------------------------------------------------------------------------
extern "C" void kernel_launch(void* const* d_in, const int* in_sizes, int n_in,
                              void* d_out, int out_size, void* d_ws, size_t ws_size,
                              hipStream_t stream) {
    const float* x   = (const float*)d_in[0];   // (T,B,2) fp32
    const float* raw = (const float*)d_in[1];   // (B,34)  fp32
    float* out = (float*)d_out;                 // (T,B,6) fp32
    float* dummy = (float*)d_ws;                // 32 KB sink for lanes 6,7

    abcd_fused<<<dim3(NB / 8), dim3(64), 0, stream>>>(x, raw, out, dummy);
}

// Round 9
// 142.654 us; speedup vs baseline: 1.0833x; 1.0833x over previous
//
#include <hip/hip_runtime.h>
#include <math.h>

#define T_STEPS 730
#define NB      1000
#define LENF    15
#define NEARZ   1e-5f
#define CHUNK   10      // 730 = 73 chunks of 10

// ---------------------------------------------------------------------------
// DPP butterfly sum over each aligned group of 8 lanes, pure VALU:
// quad_perm xor1 (0xB1), quad_perm xor2 (0x4E), row_half_mirror (0x141).
// ---------------------------------------------------------------------------
template <int CTRL>
__device__ __forceinline__ float dpp_mov(float x) {
    int xi = __builtin_bit_cast(int, x);
    int r  = __builtin_amdgcn_update_dpp(0, xi, CTRL, 0xF, 0xF, true);
    return __builtin_bit_cast(float, r);
}
__device__ __forceinline__ float sum8(float v) {
    v += dpp_mov<0xB1>(v);
    v += dpp_mov<0x4E>(v);
    v += dpp_mov<0x141>(v);
    return v;   // all 8 lanes of the group hold the group sum
}

// One physics + reduce + store step. No FIR, no hist, single linear store.
#define STEP(CURV)                                                             \
  {                                                                            \
    float pcp = (CURV).x, pet = (CURV).y;                                      \
    float W     = pcp + S;                                                     \
    float term  = fmaf(W, inv2a, pb2a);                                        \
    float disc  = fmaf(term, term, -(W * boa));                                \
    float r     = __builtin_amdgcn_sqrtf(fmaxf(disc, NEARZ));                  \
    float Y     = term - r;                                                    \
    float e     = __builtin_amdgcn_exp2f(pet * ninvbl2);                       \
    float Sn    = Y * e;                                                       \
    float AET   = Y - Sn;                                                      \
    float avail = W - Y;                                                       \
    float Qs    = omc * avail;                                                 \
    float Gn    = fmaf(pc, avail, G) * inv1pd;                                 \
    float Qg    = pd * Gn;                                                     \
    S = Sn; G = Gn;                                                            \
    float qs_s = sum8(Qs);                                                     \
    float qg_s = sum8(Qg);                                                     \
    float ae_s = sum8(AET);                                                    \
    float s_s  = sum8(Sn);                                                     \
    float g_s  = sum8(Gn);                                                     \
    float v = qs_s;                                                            \
    v = (m == 1) ? qg_s : v;                                                   \
    v = (m == 2) ? ae_s : v;                                                   \
    v = (m == 3) ? s_s  : v;                                                   \
    v = (m >= 4) ? g_s  : v;                                                   \
    *optr = v * 0.125f;                                                        \
    optr += incr;                                                              \
  }

// ---------------------------------------------------------------------------
// k1: the serial scan. Block = 64 = 1 wave = 8 basins x 8 members; grid 125.
// Per step: physics + 5 DPP sums + 4 selects + ONE store. The FIR/select/
// scatter tail (R6/R7 post-mortem: ~180 cyc/step of in-order serialization)
// is moved to conv_kernel. x via A/B/C triple-buffered chunks, prefetched
// 2 chunks (20 steps ~ 1600 cyc) ahead, pinned by sched_barrier(0).
// ---------------------------------------------------------------------------
__global__ __launch_bounds__(64, 1) void scan_kernel(const float* __restrict__ x,
                                                     const float* __restrict__ raw,
                                                     float* __restrict__ out,
                                                     float* __restrict__ qs_ws,
                                                     float* __restrict__ qg_ws,
                                                     float* __restrict__ dummy) {
    const int L  = threadIdx.x;
    const int lb = L >> 3;                 // local basin 0..7
    const int m  = L & 7;                  // member / role
    const int b  = blockIdx.x * 8 + lb;    // global basin

    // raw layout (B,34) = [a(8), b(8), c(8), d(8), ra, rb]
    const float* rp = raw + b * 34;
    float pa = rp[0 * 8 + m] * 0.9f + 0.1f;
    float pb = rp[1 * 8 + m] * 450.0f + 50.0f;
    float pc = rp[2 * 8 + m];
    float pd = rp[3 * 8 + m] * 0.89f + 0.01f;

    float inv2a   = 1.0f / (2.0f * pa);
    float pb2a    = pb * inv2a;
    float boa     = pb / pa;
    float ninvbl2 = -1.4426950408889634f / pb;   // exp(-pet/b)=exp2(pet*this)
    float omc     = 1.0f - pc;
    float inv1pd  = 1.0f / (1.0f + pd);

    // per-lane output stream: m0 -> qs plane, m1 -> qg plane (layout [t*NB+b],
    // exactly what conv_kernel reads), m2..4 -> out ch3..5, m5..7 -> dummy.
    float* optr;
    long long incr;
    if      (m == 0) { optr = qs_ws + b;                      incr = NB;     }
    else if (m == 1) { optr = qg_ws + b;                      incr = NB;     }
    else if (m <= 4) { optr = out + (long long)b * 6 + m + 1; incr = NB * 6; }
    else             { optr = dummy + (blockIdx.x * 64 + L);  incr = 0;      }

    float S = 50.0f, G = 10.0f;

    const float2* __restrict__ xf = (const float2*)x;   // (T,B) of (p,pet)

    float2 A[CHUNK], B[CHUNK], C[CHUNK];
#pragma unroll
    for (int j = 0; j < CHUNK; ++j) A[j] = xf[(0 * CHUNK + j) * NB + b];
#pragma unroll
    for (int j = 0; j < CHUNK; ++j) B[j] = xf[(1 * CHUNK + j) * NB + b];

    // 24 groups x 3 chunks (A,B,C roles rotate; chunk c consumed at phase c,
    // prefetched at phase c-2) + tail chunk 72 (landed in A at cg=23).
    for (int cg = 0; cg < 24; ++cg) {
        const int c0 = 3 * cg;
        // --- chunk c0: consume A, prefetch chunk c0+2 into C (<=71, no clamp)
#pragma unroll
        for (int j = 0; j < CHUNK; ++j) C[j] = xf[((c0 + 2) * CHUNK + j) * NB + b];
        __builtin_amdgcn_sched_barrier(0);
#pragma unroll
        for (int j = 0; j < CHUNK; ++j) STEP(A[j]);
        // --- chunk c0+1: consume B, prefetch chunk c0+3 into A (<=72, no clamp)
#pragma unroll
        for (int j = 0; j < CHUNK; ++j) A[j] = xf[((c0 + 3) * CHUNK + j) * NB + b];
        __builtin_amdgcn_sched_barrier(0);
#pragma unroll
        for (int j = 0; j < CHUNK; ++j) STEP(B[j]);
        // --- chunk c0+2: consume C, prefetch chunk c0+4 into B (clamp at end)
#pragma unroll
        for (int j = 0; j < CHUNK; ++j) {
            int t = (c0 + 4) * CHUNK + j;
            t = t < T_STEPS ? t : (T_STEPS - 1);
            B[j] = xf[t * NB + b];
        }
        __builtin_amdgcn_sched_barrier(0);
#pragma unroll
        for (int j = 0; j < CHUNK; ++j) STEP(C[j]);
    }
    // tail: chunk 72 (t = 720..729), resident in A
#pragma unroll
    for (int j = 0; j < CHUNK; ++j) STEP(A[j]);
}

// ---------------------------------------------------------------------------
// k0: gamma unit hydrograph, transposed layout UH_T[k*NB + b].
// gammaln(aa) and aa*log(theta) cancel under normalization.
// ---------------------------------------------------------------------------
__global__ __launch_bounds__(256) void uh_kernel(const float* __restrict__ raw,
                                                 float* __restrict__ uh) {
    int b = blockIdx.x * 256 + threadIdx.x;
    if (b >= NB) return;
    float ra = raw[b * 34 + 32] * 2.9f;
    float rb = raw[b * 34 + 33] * 6.5f;
    float aa = fmaxf(ra, 0.0f) + 0.1f;
    float th = fmaxf(rb, 0.0f) + 0.5f;
    float inv_th = 1.0f / th;
    float am1 = aa - 1.0f;
    float w[LENF];
    float s = 0.0f;
#pragma unroll
    for (int k = 0; k < LENF; ++k) {
        float t = (float)k + 0.5f;
        float lw = am1 * __logf(t) - t * inv_th;
        w[k] = __expf(lw);
        s += w[k];
    }
    float invs = 1.0f / s;
#pragma unroll
    for (int k = 0; k < LENF; ++k) uh[k * NB + b] = w[k] * invs;
}

// ---------------------------------------------------------------------------
// k2: 15-tap causal convolution per (t, basin); writes out ch0..2.
// Qsim conv = Qsurf conv + Qgw conv by linearity. (R1's proven kernel.)
// ---------------------------------------------------------------------------
__global__ __launch_bounds__(256) void conv_kernel(const float* __restrict__ qs_ws,
                                                   const float* __restrict__ qg_ws,
                                                   const float* __restrict__ uh,
                                                   float* __restrict__ out) {
    int b = blockIdx.x * 256 + threadIdx.x;
    int t = blockIdx.y;
    if (b >= NB) return;
    float ys = 0.0f, yg = 0.0f;
    int kmax = t < (LENF - 1) ? t : (LENF - 1);
    for (int k = 0; k <= kmax; ++k) {
        float w = uh[k * NB + b];
        ys = fmaf(qs_ws[(t - k) * NB + b], w, ys);
        yg = fmaf(qg_ws[(t - k) * NB + b], w, yg);
    }
    float* o = out + (t * NB + b) * 6;
    o[0] = ys + yg;
    o[1] = ys;
    o[2] = yg;
}

// ---------------------------------------------------------------------------
extern "C" void kernel_launch(void* const* d_in, const int* in_sizes, int n_in,
                              void* d_out, int out_size, void* d_ws, size_t ws_size,
                              hipStream_t stream) {
    const float* x   = (const float*)d_in[0];   // (T,B,2) fp32
    const float* raw = (const float*)d_in[1];   // (B,34)  fp32
    float* out = (float*)d_out;                 // (T,B,6) fp32

    // ws (floats): qs[730000] | qg[730000] | uh[15000] | dummy[8000] = 5.9 MB
    float* qs = (float*)d_ws;
    float* qg = qs + (size_t)T_STEPS * NB;
    float* uh = qg + (size_t)T_STEPS * NB;
    float* dm = uh + (size_t)LENF * NB;

    uh_kernel  <<<dim3((NB + 255) / 256),          dim3(256), 0, stream>>>(raw, uh);
    scan_kernel<<<dim3(NB / 8),                    dim3(64),  0, stream>>>(x, raw, out, qs, qg, dm);
    conv_kernel<<<dim3((NB + 255) / 256, T_STEPS), dim3(256), 0, stream>>>(qs, qg, uh, out);
}